// Round 9
// baseline (2521.214 us; speedup 1.0000x reference)
//
#include <hip/hip_runtime.h>

#define N_NODES   100000
#define N_EDGES   1600000
#define D         64
#define N_TARGETS 100
#define N_GRAPHS  512

typedef _Float16 half4 __attribute__((ext_vector_type(4)));
typedef _Float16 half8 __attribute__((ext_vector_type(8)));

// ---------------- utility ----------------

__global__ void k_zero_i(int* __restrict__ p, int n) {
    int i = blockIdx.x * blockDim.x + threadIdx.x;
    if (i < n) p[i] = 0;
}
__global__ void k_zero_f(float* __restrict__ p, int n) {
    int i = blockIdx.x * blockDim.x + threadIdx.x;
    if (i < n) p[i] = 0.0f;
}

// ---------------- CSR build ----------------

__global__ void k_deg(const int* __restrict__ dst, int* __restrict__ deg) {
    int e = blockIdx.x * blockDim.x + threadIdx.x;
    if (e < N_EDGES) atomicAdd(&deg[dst[e]], 1);
}

__global__ void k_dinv(const int* __restrict__ deg, float* __restrict__ dinv) {
    int i = blockIdx.x * blockDim.x + threadIdx.x;
    if (i < N_NODES) dinv[i] = rsqrtf((float)deg[i] + 1.0f);  // +1 self-loop
}

__global__ void k_scan1(const int* __restrict__ deg, int* __restrict__ base,
                        int* __restrict__ bsum) {
    __shared__ int s[256];
    int t = threadIdx.x, i = blockIdx.x * 256 + t;
    int v = (i < N_NODES) ? deg[i] : 0;
    s[t] = v;
    __syncthreads();
    for (int off = 1; off < 256; off <<= 1) {
        int x = (t >= off) ? s[t - off] : 0;
        __syncthreads();
        s[t] += x;
        __syncthreads();
    }
    if (i < N_NODES) base[i] = s[t] - v;
    if (t == 255) bsum[blockIdx.x] = s[255];
}

__global__ void k_scan2(int* __restrict__ bsum, int nb) {
    __shared__ int s[512];
    int t = threadIdx.x;
    int v = (t < nb) ? bsum[t] : 0;
    s[t] = v;
    __syncthreads();
    for (int off = 1; off < 512; off <<= 1) {
        int x = (t >= off) ? s[t - off] : 0;
        __syncthreads();
        s[t] += x;
        __syncthreads();
    }
    if (t < nb) bsum[t] = s[t] - v;
}

__global__ void k_scan3(int* __restrict__ base, const int* __restrict__ bsum,
                        int* __restrict__ cursor) {
    int i = blockIdx.x * blockDim.x + threadIdx.x;
    if (i < N_NODES) {
        base[i] += bsum[i >> 8];
        cursor[i] = 0;
    }
    if (i == 0) base[N_NODES] = N_EDGES;
}

// init 8 bucket write-cursors to bucket base positions (bucket = dst>>14)
__global__ void k_init8(const int* __restrict__ base, int* __restrict__ gcur8) {
    int t = threadIdx.x;
    if (t < 8) {
        int nb = t << 14;
        if (nb > N_NODES) nb = N_NODES;
        gcur8[t] = base[nb];
    }
}

// ---- stage A: ballot-based partition of edges into 7 dst-buckets ----
// No LDS. Per 64-edge wave step, per bucket: one ballot + one global atomic
// chunk-claim + a ~72B clustered u64 write. ebuck positions == final CSR edge
// positions' bucket ranges (gcur8 starts at base[bucket_start]).
__global__ void __launch_bounds__(256)
k_partA(const int* __restrict__ src, const int* __restrict__ dst,
        int* __restrict__ gcur8, unsigned long long* __restrict__ ebuck) {
    const int TT = 1024 * 256;
    const int ITERS = (N_EDGES + TT - 1) / TT;  // 7
    int tid  = blockIdx.x * 256 + threadIdx.x;
    int lane = threadIdx.x & 63;
    unsigned long long lmask_lt = (lane == 63) ? 0x7fffffffffffffffull
                                               : ((1ull << lane) - 1);
    for (int it = 0; it < ITERS; ++it) {
        int e = tid + it * TT;
        int b = 8;
        unsigned long long pk = 0;
        if (e < N_EDGES) {
            int d = dst[e];
            int s = src[e];
            b  = d >> 14;                                  // 0..6
            pk = ((unsigned long long)(unsigned)d << 32) | (unsigned)s;
        }
#pragma unroll
        for (int k = 0; k < 7; ++k) {
            unsigned long long mask = __ballot(b == k);
            int c = __popcll(mask);
            if (c == 0) continue;
            int leader = (int)__builtin_ctzll(mask);
            int gpv = 0;
            if (lane == leader) gpv = atomicAdd(&gcur8[k], c);
            gpv = __shfl(gpv, leader, 64);
            if (b == k) {
                int off = __popcll(mask & lmask_lt);
                ebuck[(size_t)(gpv + off)] = pk;
            }
        }
    }
}

// ---- stage B: per-bucket fill. blockIdx&7 = bucket (XCD round-robin
// heuristic -> one bucket per XCD). Each block first PRIMES its slice of the
// bucket's esrc window with volatile reads so lines are L2-allocated; the
// scattered stores then hit L2 and write back once per line.
__global__ void __launch_bounds__(256)
k_partB(const unsigned long long* __restrict__ ebuck, const int* __restrict__ base,
        int* __restrict__ cursor, int* __restrict__ esrc) {
    int b = blockIdx.x & 7;
    int j = blockIdx.x >> 3;   // chunk 0..127
    if (b >= 7) return;
    int n0 = b << 14;          // < N_NODES for b<7
    int n1 = (b + 1) << 14;  if (n1 > N_NODES) n1 = N_NODES;
    int lo = base[n0], hi = base[n1];
    int wlen = hi - lo;
    int csz = (wlen + 127) >> 7;
    int plo = lo + j * csz;
    int phi = plo + csz;  if (phi > hi) phi = hi;
    if (plo >= phi) return;

    // prime the target window slice (volatile: loads cannot be elided)
    volatile const int* ve = esrc;
    for (int p = plo + threadIdx.x; p < phi; p += 256) { (void)ve[p]; }

    for (int p = plo + threadIdx.x; p < phi; p += 256) {
        unsigned long long pk = ebuck[(size_t)p];
        int d = (int)(pk >> 32);
        int s = (int)(pk & 0xffffffffu);
        int pos = base[d] + atomicAdd(&cursor[d], 1);
        esrc[pos] = s;
    }
}

// ------ matmul: H16[row] = fp16( (relu?)X[row] @ W * dinv[row] ) ------
__global__ void __launch_bounds__(256)
k_mm(const float* __restrict__ X, const float* __restrict__ W,
     const float* __restrict__ dinv, _Float16* __restrict__ Y16, int relu) {
    __shared__ float Xs[64][68];
    __shared__ float Ws[64][68];
    int tid = threadIdx.x;
    int r0  = blockIdx.x * 64;
    {
        int lr = tid >> 4;
        int lc = (tid & 15) * 4;
#pragma unroll
        for (int i = 0; i < 4; ++i) {
            int row = lr + 16 * i;
            *(float4*)&Ws[row][lc] = *(const float4*)(W + row * 64 + lc);
            int gr = r0 + row;
            if (gr < N_NODES) {
                float4 xv = *(const float4*)(X + (size_t)gr * 64 + lc);
                if (relu) {
                    xv.x = fmaxf(xv.x, 0.0f); xv.y = fmaxf(xv.y, 0.0f);
                    xv.z = fmaxf(xv.z, 0.0f); xv.w = fmaxf(xv.w, 0.0f);
                }
                *(float4*)&Xs[row][lc] = xv;
            }
        }
    }
    __syncthreads();

    int tx = (tid & 15) * 4;
    int ty = (tid >> 4) * 4;
    float acc[4][4] = {{0.f}};

#pragma unroll
    for (int kk = 0; kk < 16; ++kk) {
        float4 a[4], w[4];
#pragma unroll
        for (int r = 0; r < 4; ++r) a[r] = *(float4*)&Xs[ty + r][kk * 4];
#pragma unroll
        for (int k = 0; k < 4; ++k) w[k] = *(float4*)&Ws[kk * 4 + k][tx];
#pragma unroll
        for (int r = 0; r < 4; ++r) {
#pragma unroll
            for (int k = 0; k < 4; ++k) {
                float av = ((const float*)&a[r])[k];
                acc[r][0] = fmaf(av, w[k].x, acc[r][0]);
                acc[r][1] = fmaf(av, w[k].y, acc[r][1]);
                acc[r][2] = fmaf(av, w[k].z, acc[r][2]);
                acc[r][3] = fmaf(av, w[k].w, acc[r][3]);
            }
        }
    }

#pragma unroll
    for (int r = 0; r < 4; ++r) {
        int gr = r0 + ty + r;
        if (gr < N_NODES) {
            float di = dinv[gr];
            half4 o;
            o.x = (_Float16)(acc[r][0] * di);
            o.y = (_Float16)(acc[r][1] * di);
            o.z = (_Float16)(acc[r][2] * di);
            o.w = (_Float16)(acc[r][3] * di);
            *(half4*)(Y16 + (size_t)gr * 64 + tx) = o;
        }
    }
}

// ---------------- pull aggregation (fp16 half8 gathers, fp32 accumulate) ----
__global__ void __launch_bounds__(256)
k_pull(const _Float16* __restrict__ H, const int* __restrict__ esrc,
       const int* __restrict__ base, const float* __restrict__ dinv,
       const float* __restrict__ b, float* __restrict__ AGG) {
    int i    = blockIdx.x * 4 + (threadIdx.x >> 6);
    int lane = threadIdx.x & 63;
    int g = lane >> 3, l = lane & 7;
    int s0 = base[i], s1 = base[i + 1];
    float acc[8] = {0.f, 0.f, 0.f, 0.f, 0.f, 0.f, 0.f, 0.f};
    if (g == 0) {
        half8 sv = *(const half8*)(H + (size_t)i * D + l * 8);
#pragma unroll
        for (int q = 0; q < 8; ++q) acc[q] = (float)sv[q];
    }

    int p = s0;
    while (p < s1) {
        int cnt = s1 - p;
        if (cnt > 64) cnt = 64;
        int ed = (lane < cnt) ? esrc[p + lane] : 0;
        int j = 0;
        for (; j + 32 <= cnt; j += 32) {
            int e0 = __shfl(ed, j + g, 64);
            int e1 = __shfl(ed, j + 8 + g, 64);
            int e2 = __shfl(ed, j + 16 + g, 64);
            int e3 = __shfl(ed, j + 24 + g, 64);
            half8 v0 = *(const half8*)(H + (size_t)e0 * D + l * 8);
            half8 v1 = *(const half8*)(H + (size_t)e1 * D + l * 8);
            half8 v2 = *(const half8*)(H + (size_t)e2 * D + l * 8);
            half8 v3 = *(const half8*)(H + (size_t)e3 * D + l * 8);
#pragma unroll
            for (int q = 0; q < 8; ++q)
                acc[q] += ((float)v0[q] + (float)v1[q]) + ((float)v2[q] + (float)v3[q]);
        }
        for (; j + 8 <= cnt; j += 8) {
            int e0 = __shfl(ed, j + g, 64);
            half8 v0 = *(const half8*)(H + (size_t)e0 * D + l * 8);
#pragma unroll
            for (int q = 0; q < 8; ++q) acc[q] += (float)v0[q];
        }
        if (j < cnt) {
            int idx = j + g;
            int e0 = __shfl(ed, idx & 63, 64);
            if (idx < cnt) {
                half8 v0 = *(const half8*)(H + (size_t)e0 * D + l * 8);
#pragma unroll
                for (int q = 0; q < 8; ++q) acc[q] += (float)v0[q];
            }
        }
        p += cnt;
    }
#pragma unroll
    for (int off = 8; off <= 32; off <<= 1) {
#pragma unroll
        for (int q = 0; q < 8; ++q)
            acc[q] += __shfl_xor(acc[q], off, 64);
    }

    if (g == 0) {
        float di = dinv[i];
        float4 bl0 = *(const float4*)(b + l * 8);
        float4 bl1 = *(const float4*)(b + l * 8 + 4);
        float4 o0 = { fmaf(acc[0], di, bl0.x), fmaf(acc[1], di, bl0.y),
                      fmaf(acc[2], di, bl0.z), fmaf(acc[3], di, bl0.w) };
        float4 o1 = { fmaf(acc[4], di, bl1.x), fmaf(acc[5], di, bl1.y),
                      fmaf(acc[6], di, bl1.z), fmaf(acc[7], di, bl1.w) };
        *(float4*)(AGG + (size_t)i * D + l * 8)     = o0;
        *(float4*)(AGG + (size_t)i * D + l * 8 + 4) = o1;
    }
}

// ---- segment-sorted pooling ----
__global__ void __launch_bounds__(256)
k_pool_seg(const float* __restrict__ H, const int* __restrict__ seg,
           float* __restrict__ pooled) {
    int wave = threadIdx.x >> 6;
    int lane = threadIdx.x & 63;
    int n0 = (blockIdx.x * 4 + wave) * 64;
    if (n0 >= N_NODES) return;
    int nEnd = n0 + 64;
    if (nEnd > N_NODES) nEnd = N_NODES;
    int cur = seg[n0];
    float acc = 0.0f;
    for (int n = n0; n < nEnd; ++n) {
        int gsg = seg[n];
        if (gsg != cur) {
            atomicAdd(&pooled[(size_t)cur * D + lane], acc);
            acc = 0.0f;
            cur = gsg;
        }
        acc += H[(size_t)n * D + lane];
    }
    atomicAdd(&pooled[(size_t)cur * D + lane], acc);
}

__global__ void k_counts(const int* __restrict__ seg, float* __restrict__ counts) {
    int i = blockIdx.x * blockDim.x + threadIdx.x;
    if (i < N_NODES) atomicAdd(&counts[seg[i]], 1.0f);
}

// ---------------- head ----------------
__global__ void k_out(const float* __restrict__ pooled, const float* __restrict__ counts,
                      const float* __restrict__ Wout, const float* __restrict__ bout,
                      float* __restrict__ out) {
    __shared__ float prow[D];
    int g = blockIdx.x;
    int t = threadIdx.x;
    if (t < D) prow[t] = pooled[(size_t)g * D + t] / fmaxf(counts[g], 1.0f);
    __syncthreads();
    if (t < N_TARGETS) {
        float acc = bout[t];
#pragma unroll
        for (int k = 0; k < D; ++k)
            acc = fmaf(prow[k], Wout[k * N_TARGETS + t], acc);
        out[g * N_TARGETS + t] = acc;
    }
}

// ---------------- driver ----------------

extern "C" void kernel_launch(void* const* d_in, const int* in_sizes, int n_in,
                              void* d_out, int out_size, void* d_ws, size_t ws_size,
                              hipStream_t stream) {
    const float* x    = (const float*)d_in[0];
    const float* W1   = (const float*)d_in[1];
    const float* b1   = (const float*)d_in[2];
    const float* W2   = (const float*)d_in[3];
    const float* b2   = (const float*)d_in[4];
    const float* W3   = (const float*)d_in[5];
    const float* b3   = (const float*)d_in[6];
    const float* Wout = (const float*)d_in[7];
    const float* bout = (const float*)d_in[8];
    const int*   eidx = (const int*)d_in[9];
    const int*   seg  = (const int*)d_in[10];
    const int* src = eidx;
    const int* dst = eidx + N_EDGES;
    float* out = (float*)d_out;

    // workspace (~47 MB); ebuck (12.8MB u64) aliases H16 (dead during CSR build)
    _Float16* H16    = (_Float16*)d_ws;                      // 6,400,000 halfs
    unsigned long long* ebuck = (unsigned long long*)d_ws;   // alias, 1.6M u64
    float*    bufB   = (float*)(H16 + (size_t)N_NODES * D);  // 6,400,000 floats (AGG)
    int*      esrc   = (int*)(bufB + (size_t)N_NODES * D);   // 1,600,000
    float*    dinv   = (float*)(esrc + N_EDGES);             // 100,000
    int*      degc   = (int*)(dinv + N_NODES);               // 100,000 (deg, then cursor)
    int*      base   = degc + N_NODES;                       // 100,001 (+pad)
    int*      bsum   = base + N_NODES + 4;                   // 512
    int*      gcur8  = bsum + 512;                           // 16
    float*    pooled = (float*)(gcur8 + 16);                 // 32,768
    float*    counts = pooled + N_GRAPHS * D;                // 512

    const int NB = (N_NODES + 255) / 256;  // 391

    // ---- CSR build ----
    k_zero_i<<<NB, 256, 0, stream>>>(degc, N_NODES);
    k_deg<<<N_EDGES / 256, 256, 0, stream>>>(dst, degc);
    k_dinv<<<NB, 256, 0, stream>>>(degc, dinv);
    k_scan1<<<NB, 256, 0, stream>>>(degc, base, bsum);
    k_scan2<<<1, 512, 0, stream>>>(bsum, NB);
    k_scan3<<<NB, 256, 0, stream>>>(base, bsum, degc);   // also zeroes cursor
    k_init8<<<1, 64, 0, stream>>>(base, gcur8);
    k_partA<<<1024, 256, 0, stream>>>(src, dst, gcur8, ebuck);
    k_partB<<<1024, 256, 0, stream>>>(ebuck, base, degc, esrc);

    // ---- 3 GCN layers ----
    const int MMB = (N_NODES + 63) / 64;  // 1563
    k_mm<<<MMB, 256, 0, stream>>>(x, W1, dinv, H16, 0);
    k_pull<<<N_NODES / 4, 256, 0, stream>>>(H16, esrc, base, dinv, b1, bufB);
    k_mm<<<MMB, 256, 0, stream>>>(bufB, W2, dinv, H16, 1);
    k_pull<<<N_NODES / 4, 256, 0, stream>>>(H16, esrc, base, dinv, b2, bufB);
    k_mm<<<MMB, 256, 0, stream>>>(bufB, W3, dinv, H16, 1);
    k_pull<<<N_NODES / 4, 256, 0, stream>>>(H16, esrc, base, dinv, b3, bufB);

    // ---- mean pool (sorted-segment) + head ----
    k_zero_f<<<(N_GRAPHS * D + N_GRAPHS + 255) / 256, 256, 0, stream>>>(pooled, N_GRAPHS * D + N_GRAPHS);
    k_counts<<<NB, 256, 0, stream>>>(seg, counts);
    k_pool_seg<<<NB, 256, 0, stream>>>(bufB, seg, pooled);

    k_out<<<N_GRAPHS, 128, 0, stream>>>(pooled, counts, Wout, bout, out);
}

// Round 10
// 641.736 us; speedup vs baseline: 3.9287x; 3.9287x over previous
//
#include <hip/hip_runtime.h>

#define N_NODES   100000
#define N_EDGES   1600000
#define D         64
#define N_TARGETS 100
#define N_GRAPHS  512

typedef _Float16 half4 __attribute__((ext_vector_type(4)));
typedef _Float16 half8 __attribute__((ext_vector_type(8)));

// ---------------- utility ----------------

__global__ void k_zero_i(int* __restrict__ p, int n) {
    int i = blockIdx.x * blockDim.x + threadIdx.x;
    if (i < n) p[i] = 0;
}
__global__ void k_zero_f(float* __restrict__ p, int n) {
    int i = blockIdx.x * blockDim.x + threadIdx.x;
    if (i < n) p[i] = 0.0f;
}

// ---------------- CSR build (R3/R7 scheme: simple scatter fill) -------------

__global__ void k_deg(const int* __restrict__ dst, int* __restrict__ deg) {
    int e = blockIdx.x * blockDim.x + threadIdx.x;
    if (e < N_EDGES) atomicAdd(&deg[dst[e]], 1);
}

// block-local exclusive scan of deg; also computes dinv (deg already loaded)
__global__ void k_scan1(const int* __restrict__ deg, int* __restrict__ base,
                        int* __restrict__ bsum, float* __restrict__ dinv) {
    __shared__ int s[256];
    int t = threadIdx.x, i = blockIdx.x * 256 + t;
    int v = (i < N_NODES) ? deg[i] : 0;
    if (i < N_NODES) dinv[i] = rsqrtf((float)v + 1.0f);  // +1 self-loop
    s[t] = v;
    __syncthreads();
    for (int off = 1; off < 256; off <<= 1) {
        int x = (t >= off) ? s[t - off] : 0;
        __syncthreads();
        s[t] += x;
        __syncthreads();
    }
    if (i < N_NODES) base[i] = s[t] - v;
    if (t == 255) bsum[blockIdx.x] = s[255];
}

__global__ void k_scan2(int* __restrict__ bsum, int nb) {
    __shared__ int s[512];
    int t = threadIdx.x;
    int v = (t < nb) ? bsum[t] : 0;
    s[t] = v;
    __syncthreads();
    for (int off = 1; off < 512; off <<= 1) {
        int x = (t >= off) ? s[t - off] : 0;
        __syncthreads();
        s[t] += x;
        __syncthreads();
    }
    if (t < nb) bsum[t] = s[t] - v;
}

__global__ void k_scan3(int* __restrict__ base, const int* __restrict__ bsum,
                        int* __restrict__ cursor) {
    int i = blockIdx.x * blockDim.x + threadIdx.x;
    if (i < N_NODES) {
        base[i] += bsum[i >> 8];
        cursor[i] = 0;
    }
    if (i == 0) base[N_NODES] = N_EDGES;
}

__global__ void k_fill(const int* __restrict__ src, const int* __restrict__ dst,
                       const int* __restrict__ base, int* __restrict__ cursor,
                       int* __restrict__ esrc) {
    int e = blockIdx.x * blockDim.x + threadIdx.x;
    if (e < N_EDGES) {
        int d = dst[e];
        int pos = base[d] + atomicAdd(&cursor[d], 1);
        esrc[pos] = src[e];
    }
}

// ------ matmul (layer 1 only): H16[row] = fp16( X[row] @ W * dinv[row] ) ----
__global__ void __launch_bounds__(256)
k_mm(const float* __restrict__ X, const float* __restrict__ W,
     const float* __restrict__ dinv, _Float16* __restrict__ Y16) {
    __shared__ float Xs[64][68];
    __shared__ float Ws[64][68];
    int tid = threadIdx.x;
    int r0  = blockIdx.x * 64;
    {
        int lr = tid >> 4;
        int lc = (tid & 15) * 4;
#pragma unroll
        for (int i = 0; i < 4; ++i) {
            int row = lr + 16 * i;
            *(float4*)&Ws[row][lc] = *(const float4*)(W + row * 64 + lc);
            int gr = r0 + row;
            if (gr < N_NODES)
                *(float4*)&Xs[row][lc] = *(const float4*)(X + (size_t)gr * 64 + lc);
        }
    }
    __syncthreads();

    int tx = (tid & 15) * 4;
    int ty = (tid >> 4) * 4;
    float acc[4][4] = {{0.f}};

#pragma unroll
    for (int kk = 0; kk < 16; ++kk) {
        float4 a[4], w[4];
#pragma unroll
        for (int r = 0; r < 4; ++r) a[r] = *(float4*)&Xs[ty + r][kk * 4];
#pragma unroll
        for (int k = 0; k < 4; ++k) w[k] = *(float4*)&Ws[kk * 4 + k][tx];
#pragma unroll
        for (int r = 0; r < 4; ++r) {
#pragma unroll
            for (int k = 0; k < 4; ++k) {
                float av = ((const float*)&a[r])[k];
                acc[r][0] = fmaf(av, w[k].x, acc[r][0]);
                acc[r][1] = fmaf(av, w[k].y, acc[r][1]);
                acc[r][2] = fmaf(av, w[k].z, acc[r][2]);
                acc[r][3] = fmaf(av, w[k].w, acc[r][3]);
            }
        }
    }

#pragma unroll
    for (int r = 0; r < 4; ++r) {
        int gr = r0 + ty + r;
        if (gr < N_NODES) {
            float di = dinv[gr];
            half4 o;
            o.x = (_Float16)(acc[r][0] * di);
            o.y = (_Float16)(acc[r][1] * di);
            o.z = (_Float16)(acc[r][2] * di);
            o.w = (_Float16)(acc[r][3] * di);
            *(half4*)(Y16 + (size_t)gr * 64 + tx) = o;
        }
    }
}

// ---- fused pull + next-layer matmul ----
// Gather phase = R7 k_pull (half8, slot layout). After the full butterfly
// reduction EVERY lane holds the node's feature chunk [8l,8l+8). Epilogue:
// a = relu(acc*dinv + b_in); out[lane] = (Σ_k a_k * W[k][lane]) * dinv;
// store fp16 row for the next pull. Kills the separate mm + AGG round-trip.
__global__ void __launch_bounds__(256)
k_pullmm(const _Float16* __restrict__ H, const int* __restrict__ esrc,
         const int* __restrict__ base, const float* __restrict__ dinv,
         const float* __restrict__ b_in, const float* __restrict__ W,
         _Float16* __restrict__ Hout) {
    __shared__ float Ws[D * D];
    {
        float4* Wv = (float4*)Ws;
        const float4* Wg = (const float4*)W;
#pragma unroll
        for (int q = 0; q < 4; ++q)
            Wv[threadIdx.x * 4 + q] = Wg[threadIdx.x * 4 + q];
    }
    __syncthreads();

    int i    = blockIdx.x * 4 + (threadIdx.x >> 6);
    int lane = threadIdx.x & 63;
    int g = lane >> 3, l = lane & 7;
    int s0 = base[i], s1 = base[i + 1];
    float acc[8] = {0.f, 0.f, 0.f, 0.f, 0.f, 0.f, 0.f, 0.f};
    if (g == 0) {
        half8 sv = *(const half8*)(H + (size_t)i * D + l * 8);
#pragma unroll
        for (int q = 0; q < 8; ++q) acc[q] = (float)sv[q];
    }

    int p = s0;
    while (p < s1) {
        int cnt = s1 - p;
        if (cnt > 64) cnt = 64;
        int ed = (lane < cnt) ? esrc[p + lane] : 0;
        int j = 0;
        for (; j + 32 <= cnt; j += 32) {
            int e0 = __shfl(ed, j + g, 64);
            int e1 = __shfl(ed, j + 8 + g, 64);
            int e2 = __shfl(ed, j + 16 + g, 64);
            int e3 = __shfl(ed, j + 24 + g, 64);
            half8 v0 = *(const half8*)(H + (size_t)e0 * D + l * 8);
            half8 v1 = *(const half8*)(H + (size_t)e1 * D + l * 8);
            half8 v2 = *(const half8*)(H + (size_t)e2 * D + l * 8);
            half8 v3 = *(const half8*)(H + (size_t)e3 * D + l * 8);
#pragma unroll
            for (int q = 0; q < 8; ++q)
                acc[q] += ((float)v0[q] + (float)v1[q]) + ((float)v2[q] + (float)v3[q]);
        }
        for (; j + 8 <= cnt; j += 8) {
            int e0 = __shfl(ed, j + g, 64);
            half8 v0 = *(const half8*)(H + (size_t)e0 * D + l * 8);
#pragma unroll
            for (int q = 0; q < 8; ++q) acc[q] += (float)v0[q];
        }
        if (j < cnt) {
            int idx = j + g;
            int e0 = __shfl(ed, idx & 63, 64);
            if (idx < cnt) {
                half8 v0 = *(const half8*)(H + (size_t)e0 * D + l * 8);
#pragma unroll
                for (int q = 0; q < 8; ++q) acc[q] += (float)v0[q];
            }
        }
        p += cnt;
    }
#pragma unroll
    for (int off = 8; off <= 32; off <<= 1) {
#pragma unroll
        for (int q = 0; q < 8; ++q)
            acc[q] += __shfl_xor(acc[q], off, 64);
    }
    // all lanes now hold the full reduced row (chunk l*8..l*8+7 in acc[0..7])

    float di = dinv[i];
    float a[8];
    float4 bl0 = *(const float4*)(b_in + l * 8);
    float4 bl1 = *(const float4*)(b_in + l * 8 + 4);
    a[0] = fmaxf(fmaf(acc[0], di, bl0.x), 0.f);
    a[1] = fmaxf(fmaf(acc[1], di, bl0.y), 0.f);
    a[2] = fmaxf(fmaf(acc[2], di, bl0.z), 0.f);
    a[3] = fmaxf(fmaf(acc[3], di, bl0.w), 0.f);
    a[4] = fmaxf(fmaf(acc[4], di, bl1.x), 0.f);
    a[5] = fmaxf(fmaf(acc[5], di, bl1.y), 0.f);
    a[6] = fmaxf(fmaf(acc[6], di, bl1.z), 0.f);
    a[7] = fmaxf(fmaf(acc[7], di, bl1.w), 0.f);

    float o = 0.f;
#pragma unroll
    for (int k = 0; k < D; ++k) {
        float ak = __shfl(a[k & 7], k >> 3, 64);
        o = fmaf(ak, Ws[k * D + lane], o);   // lane-stride 1 -> 2-way bank, free
    }
    Hout[(size_t)i * D + lane] = (_Float16)(o * di);
}

// ---------------- final pull (layer 3): AGG fp32 out for pooling ----------
__global__ void __launch_bounds__(256)
k_pull(const _Float16* __restrict__ H, const int* __restrict__ esrc,
       const int* __restrict__ base, const float* __restrict__ dinv,
       const float* __restrict__ b, float* __restrict__ AGG) {
    int i    = blockIdx.x * 4 + (threadIdx.x >> 6);
    int lane = threadIdx.x & 63;
    int g = lane >> 3, l = lane & 7;
    int s0 = base[i], s1 = base[i + 1];
    float acc[8] = {0.f, 0.f, 0.f, 0.f, 0.f, 0.f, 0.f, 0.f};
    if (g == 0) {
        half8 sv = *(const half8*)(H + (size_t)i * D + l * 8);
#pragma unroll
        for (int q = 0; q < 8; ++q) acc[q] = (float)sv[q];
    }

    int p = s0;
    while (p < s1) {
        int cnt = s1 - p;
        if (cnt > 64) cnt = 64;
        int ed = (lane < cnt) ? esrc[p + lane] : 0;
        int j = 0;
        for (; j + 32 <= cnt; j += 32) {
            int e0 = __shfl(ed, j + g, 64);
            int e1 = __shfl(ed, j + 8 + g, 64);
            int e2 = __shfl(ed, j + 16 + g, 64);
            int e3 = __shfl(ed, j + 24 + g, 64);
            half8 v0 = *(const half8*)(H + (size_t)e0 * D + l * 8);
            half8 v1 = *(const half8*)(H + (size_t)e1 * D + l * 8);
            half8 v2 = *(const half8*)(H + (size_t)e2 * D + l * 8);
            half8 v3 = *(const half8*)(H + (size_t)e3 * D + l * 8);
#pragma unroll
            for (int q = 0; q < 8; ++q)
                acc[q] += ((float)v0[q] + (float)v1[q]) + ((float)v2[q] + (float)v3[q]);
        }
        for (; j + 8 <= cnt; j += 8) {
            int e0 = __shfl(ed, j + g, 64);
            half8 v0 = *(const half8*)(H + (size_t)e0 * D + l * 8);
#pragma unroll
            for (int q = 0; q < 8; ++q) acc[q] += (float)v0[q];
        }
        if (j < cnt) {
            int idx = j + g;
            int e0 = __shfl(ed, idx & 63, 64);
            if (idx < cnt) {
                half8 v0 = *(const half8*)(H + (size_t)e0 * D + l * 8);
#pragma unroll
                for (int q = 0; q < 8; ++q) acc[q] += (float)v0[q];
            }
        }
        p += cnt;
    }
#pragma unroll
    for (int off = 8; off <= 32; off <<= 1) {
#pragma unroll
        for (int q = 0; q < 8; ++q)
            acc[q] += __shfl_xor(acc[q], off, 64);
    }

    if (g == 0) {
        float di = dinv[i];
        float4 bl0 = *(const float4*)(b + l * 8);
        float4 bl1 = *(const float4*)(b + l * 8 + 4);
        float4 o0 = { fmaf(acc[0], di, bl0.x), fmaf(acc[1], di, bl0.y),
                      fmaf(acc[2], di, bl0.z), fmaf(acc[3], di, bl0.w) };
        float4 o1 = { fmaf(acc[4], di, bl1.x), fmaf(acc[5], di, bl1.y),
                      fmaf(acc[6], di, bl1.z), fmaf(acc[7], di, bl1.w) };
        *(float4*)(AGG + (size_t)i * D + l * 8)     = o0;
        *(float4*)(AGG + (size_t)i * D + l * 8 + 4) = o1;
    }
}

// ---- segment-sorted pooling (+ fused counts via run lengths) ----
__global__ void __launch_bounds__(256)
k_pool_seg(const float* __restrict__ H, const int* __restrict__ seg,
           float* __restrict__ pooled, float* __restrict__ counts) {
    int wave = threadIdx.x >> 6;
    int lane = threadIdx.x & 63;
    int n0 = (blockIdx.x * 4 + wave) * 64;
    if (n0 >= N_NODES) return;
    int nEnd = n0 + 64;
    if (nEnd > N_NODES) nEnd = N_NODES;
    int cur = seg[n0];
    float acc = 0.0f;
    int run = 0;
    for (int n = n0; n < nEnd; ++n) {
        int gsg = seg[n];  // wave-uniform
        if (gsg != cur) {
            atomicAdd(&pooled[(size_t)cur * D + lane], acc);
            if (lane == 0) atomicAdd(&counts[cur], (float)run);
            acc = 0.0f; run = 0;
            cur = gsg;
        }
        acc += H[(size_t)n * D + lane];
        run += 1;
    }
    atomicAdd(&pooled[(size_t)cur * D + lane], acc);
    if (lane == 0) atomicAdd(&counts[cur], (float)run);
}

// ---------------- head ----------------
__global__ void k_out(const float* __restrict__ pooled, const float* __restrict__ counts,
                      const float* __restrict__ Wout, const float* __restrict__ bout,
                      float* __restrict__ out) {
    __shared__ float prow[D];
    int g = blockIdx.x;
    int t = threadIdx.x;
    if (t < D) prow[t] = pooled[(size_t)g * D + t] / fmaxf(counts[g], 1.0f);
    __syncthreads();
    if (t < N_TARGETS) {
        float acc = bout[t];
#pragma unroll
        for (int k = 0; k < D; ++k)
            acc = fmaf(prow[k], Wout[k * N_TARGETS + t], acc);
        out[g * N_TARGETS + t] = acc;
    }
}

// ---------------- driver ----------------

extern "C" void kernel_launch(void* const* d_in, const int* in_sizes, int n_in,
                              void* d_out, int out_size, void* d_ws, size_t ws_size,
                              hipStream_t stream) {
    const float* x    = (const float*)d_in[0];
    const float* W1   = (const float*)d_in[1];
    const float* b1   = (const float*)d_in[2];
    const float* W2   = (const float*)d_in[3];
    const float* b2   = (const float*)d_in[4];
    const float* W3   = (const float*)d_in[5];
    const float* b3   = (const float*)d_in[6];
    const float* Wout = (const float*)d_in[7];
    const float* bout = (const float*)d_in[8];
    const int*   eidx = (const int*)d_in[9];
    const int*   seg  = (const int*)d_in[10];
    const int* src = eidx;
    const int* dst = eidx + N_EDGES;
    float* out = (float*)d_out;

    // workspace layout (~47 MB)
    _Float16* H16A   = (_Float16*)d_ws;                       // 6.4M halfs
    _Float16* H16B   = H16A + (size_t)N_NODES * D;            // 6.4M halfs
    float*    AGG    = (float*)(H16B + (size_t)N_NODES * D);  // 6.4M floats
    int*      esrc   = (int*)(AGG + (size_t)N_NODES * D);     // 1.6M
    float*    dinv   = (float*)(esrc + N_EDGES);              // 100k
    int*      degc   = (int*)(dinv + N_NODES);                // 100k (deg, then cursor)
    int*      base   = degc + N_NODES;                        // 100k+1 (+pad)
    int*      bsum   = base + N_NODES + 4;                    // 512
    float*    pooled = (float*)(bsum + 512);                  // 32768
    float*    counts = pooled + N_GRAPHS * D;                 // 512

    const int NB = (N_NODES + 255) / 256;  // 391

    // ---- CSR build ----
    k_zero_i<<<NB, 256, 0, stream>>>(degc, N_NODES);
    k_deg<<<N_EDGES / 256, 256, 0, stream>>>(dst, degc);
    k_scan1<<<NB, 256, 0, stream>>>(degc, base, bsum, dinv);
    k_scan2<<<1, 512, 0, stream>>>(bsum, NB);
    k_scan3<<<NB, 256, 0, stream>>>(base, bsum, degc);
    k_fill<<<N_EDGES / 256, 256, 0, stream>>>(src, dst, base, degc, esrc);

    // ---- 3 GCN layers (mm1 separate; mm2/mm3 fused into pulls) ----
    const int MMB = (N_NODES + 63) / 64;  // 1563
    k_mm<<<MMB, 256, 0, stream>>>(x, W1, dinv, H16A);
    k_pullmm<<<N_NODES / 4, 256, 0, stream>>>(H16A, esrc, base, dinv, b1, W2, H16B);
    k_pullmm<<<N_NODES / 4, 256, 0, stream>>>(H16B, esrc, base, dinv, b2, W3, H16A);
    k_pull<<<N_NODES / 4, 256, 0, stream>>>(H16A, esrc, base, dinv, b3, AGG);

    // ---- mean pool (sorted-segment, fused counts) + head ----
    k_zero_f<<<(N_GRAPHS * D + N_GRAPHS + 255) / 256, 256, 0, stream>>>(pooled, N_GRAPHS * D + N_GRAPHS);
    k_pool_seg<<<NB, 256, 0, stream>>>(AGG, seg, pooled, counts);

    k_out<<<N_GRAPHS, 128, 0, stream>>>(pooled, counts, Wout, bout, out);
}

// Round 11
// 541.611 us; speedup vs baseline: 4.6550x; 1.1849x over previous
//
#include <hip/hip_runtime.h>

#define N_NODES   100000
#define N_EDGES   1600000
#define D         64
#define N_TARGETS 100
#define N_GRAPHS  512

typedef _Float16 half4 __attribute__((ext_vector_type(4)));
typedef _Float16 half8 __attribute__((ext_vector_type(8)));

// ---------------- utility ----------------

__global__ void k_zero_i(int* __restrict__ p, int n) {
    int i = blockIdx.x * blockDim.x + threadIdx.x;
    if (i < n) p[i] = 0;
}
__global__ void k_zero_f(float* __restrict__ p, int n) {
    int i = blockIdx.x * blockDim.x + threadIdx.x;
    if (i < n) p[i] = 0.0f;
}

// ---------------- CSR build (simple scatter fill — measured plateau) --------

__global__ void k_deg(const int* __restrict__ dst, int* __restrict__ deg) {
    int e = blockIdx.x * blockDim.x + threadIdx.x;
    if (e < N_EDGES) atomicAdd(&deg[dst[e]], 1);
}

// block-local exclusive scan of deg; also computes dinv (deg already loaded)
__global__ void k_scan1(const int* __restrict__ deg, int* __restrict__ base,
                        int* __restrict__ bsum, float* __restrict__ dinv) {
    __shared__ int s[256];
    int t = threadIdx.x, i = blockIdx.x * 256 + t;
    int v = (i < N_NODES) ? deg[i] : 0;
    if (i < N_NODES) dinv[i] = rsqrtf((float)v + 1.0f);  // +1 self-loop
    s[t] = v;
    __syncthreads();
    for (int off = 1; off < 256; off <<= 1) {
        int x = (t >= off) ? s[t - off] : 0;
        __syncthreads();
        s[t] += x;
        __syncthreads();
    }
    if (i < N_NODES) base[i] = s[t] - v;
    if (t == 255) bsum[blockIdx.x] = s[255];
}

__global__ void k_scan2(int* __restrict__ bsum, int nb) {
    __shared__ int s[512];
    int t = threadIdx.x;
    int v = (t < nb) ? bsum[t] : 0;
    s[t] = v;
    __syncthreads();
    for (int off = 1; off < 512; off <<= 1) {
        int x = (t >= off) ? s[t - off] : 0;
        __syncthreads();
        s[t] += x;
        __syncthreads();
    }
    if (t < nb) bsum[t] = s[t] - v;
}

__global__ void k_scan3(int* __restrict__ base, const int* __restrict__ bsum,
                        int* __restrict__ cursor) {
    int i = blockIdx.x * blockDim.x + threadIdx.x;
    if (i < N_NODES) {
        base[i] += bsum[i >> 8];
        cursor[i] = 0;
    }
    if (i == 0) base[N_NODES] = N_EDGES;
}

__global__ void k_fill(const int* __restrict__ src, const int* __restrict__ dst,
                       const int* __restrict__ base, int* __restrict__ cursor,
                       int* __restrict__ esrc) {
    int e = blockIdx.x * blockDim.x + threadIdx.x;
    if (e < N_EDGES) {
        int d = dst[e];
        int pos = base[d] + atomicAdd(&cursor[d], 1);
        esrc[pos] = src[e];
    }
}

// ------ matmul (layer 1 only): H16[row] = fp16( X[row] @ W * dinv[row] ) ----
__global__ void __launch_bounds__(256)
k_mm(const float* __restrict__ X, const float* __restrict__ W,
     const float* __restrict__ dinv, _Float16* __restrict__ Y16) {
    __shared__ float Xs[64][68];
    __shared__ float Ws[64][68];
    int tid = threadIdx.x;
    int r0  = blockIdx.x * 64;
    {
        int lr = tid >> 4;
        int lc = (tid & 15) * 4;
#pragma unroll
        for (int i = 0; i < 4; ++i) {
            int row = lr + 16 * i;
            *(float4*)&Ws[row][lc] = *(const float4*)(W + row * 64 + lc);
            int gr = r0 + row;
            if (gr < N_NODES)
                *(float4*)&Xs[row][lc] = *(const float4*)(X + (size_t)gr * 64 + lc);
        }
    }
    __syncthreads();

    int tx = (tid & 15) * 4;
    int ty = (tid >> 4) * 4;
    float acc[4][4] = {{0.f}};

#pragma unroll
    for (int kk = 0; kk < 16; ++kk) {
        float4 a[4], w[4];
#pragma unroll
        for (int r = 0; r < 4; ++r) a[r] = *(float4*)&Xs[ty + r][kk * 4];
#pragma unroll
        for (int k = 0; k < 4; ++k) w[k] = *(float4*)&Ws[kk * 4 + k][tx];
#pragma unroll
        for (int r = 0; r < 4; ++r) {
#pragma unroll
            for (int k = 0; k < 4; ++k) {
                float av = ((const float*)&a[r])[k];
                acc[r][0] = fmaf(av, w[k].x, acc[r][0]);
                acc[r][1] = fmaf(av, w[k].y, acc[r][1]);
                acc[r][2] = fmaf(av, w[k].z, acc[r][2]);
                acc[r][3] = fmaf(av, w[k].w, acc[r][3]);
            }
        }
    }

#pragma unroll
    for (int r = 0; r < 4; ++r) {
        int gr = r0 + ty + r;
        if (gr < N_NODES) {
            float di = dinv[gr];
            half4 o;
            o.x = (_Float16)(acc[r][0] * di);
            o.y = (_Float16)(acc[r][1] * di);
            o.z = (_Float16)(acc[r][2] * di);
            o.w = (_Float16)(acc[r][3] * di);
            *(half4*)(Y16 + (size_t)gr * 64 + tx) = o;
        }
    }
}

// ---- fused pull + next-layer matmul (low-DS epilogue) ----
// Gather = R7 pull (half8 slot layout). Butterfly across slots g (needed
// before the nonlinear relu). Then lane (g,l) holds full a-chunk l; it
// computes partials for OUTPUT chunk g via an 8x8 W block (8 ds_read_b128
// of fp16 W, conflict-free layout), reduces across l with shfl_xor(1,2,4),
// and lanes l==0 store one half8. ~56 DS ops/node vs ~150 in R10.
__global__ void __launch_bounds__(256)
k_pullmm(const _Float16* __restrict__ H, const int* __restrict__ esrc,
         const int* __restrict__ base, const float* __restrict__ dinv,
         const float* __restrict__ b_in, const float* __restrict__ W,
         _Float16* __restrict__ Hout) {
    __shared__ _Float16 Wh[D * D];   // [k][f] fp16, 8KB
    {
        // stage + convert: thread t handles 8-elem groups t and t+256
        for (int idx = threadIdx.x; idx < (D * D) / 8; idx += 256) {
            float4 w0 = *(const float4*)(W + idx * 8);
            float4 w1 = *(const float4*)(W + idx * 8 + 4);
            half8 h;
            h[0] = (_Float16)w0.x; h[1] = (_Float16)w0.y;
            h[2] = (_Float16)w0.z; h[3] = (_Float16)w0.w;
            h[4] = (_Float16)w1.x; h[5] = (_Float16)w1.y;
            h[6] = (_Float16)w1.z; h[7] = (_Float16)w1.w;
            *(half8*)&Wh[idx * 8] = h;
        }
    }
    __syncthreads();

    int i    = blockIdx.x * 4 + (threadIdx.x >> 6);
    int lane = threadIdx.x & 63;
    int g = lane >> 3, l = lane & 7;
    int s0 = base[i], s1 = base[i + 1];
    float acc[8] = {0.f, 0.f, 0.f, 0.f, 0.f, 0.f, 0.f, 0.f};
    if (g == 0) {
        half8 sv = *(const half8*)(H + (size_t)i * D + l * 8);
#pragma unroll
        for (int q = 0; q < 8; ++q) acc[q] = (float)sv[q];
    }

    int p = s0;
    while (p < s1) {
        int cnt = s1 - p;
        if (cnt > 64) cnt = 64;
        int ed = (lane < cnt) ? esrc[p + lane] : 0;
        int j = 0;
        for (; j + 32 <= cnt; j += 32) {
            int e0 = __shfl(ed, j + g, 64);
            int e1 = __shfl(ed, j + 8 + g, 64);
            int e2 = __shfl(ed, j + 16 + g, 64);
            int e3 = __shfl(ed, j + 24 + g, 64);
            half8 v0 = *(const half8*)(H + (size_t)e0 * D + l * 8);
            half8 v1 = *(const half8*)(H + (size_t)e1 * D + l * 8);
            half8 v2 = *(const half8*)(H + (size_t)e2 * D + l * 8);
            half8 v3 = *(const half8*)(H + (size_t)e3 * D + l * 8);
#pragma unroll
            for (int q = 0; q < 8; ++q)
                acc[q] += ((float)v0[q] + (float)v1[q]) + ((float)v2[q] + (float)v3[q]);
        }
        for (; j + 8 <= cnt; j += 8) {
            int e0 = __shfl(ed, j + g, 64);
            half8 v0 = *(const half8*)(H + (size_t)e0 * D + l * 8);
#pragma unroll
            for (int q = 0; q < 8; ++q) acc[q] += (float)v0[q];
        }
        if (j < cnt) {
            int idx = j + g;
            int e0 = __shfl(ed, idx & 63, 64);
            if (idx < cnt) {
                half8 v0 = *(const half8*)(H + (size_t)e0 * D + l * 8);
#pragma unroll
                for (int q = 0; q < 8; ++q) acc[q] += (float)v0[q];
            }
        }
        p += cnt;
    }
    // reduce across slots g (lane bits 3..5) -> every lane: full chunk l
#pragma unroll
    for (int off = 8; off <= 32; off <<= 1) {
#pragma unroll
        for (int q = 0; q < 8; ++q)
            acc[q] += __shfl_xor(acc[q], off, 64);
    }

    float di = dinv[i];
    float a[8];
    {
        float4 bl0 = *(const float4*)(b_in + l * 8);
        float4 bl1 = *(const float4*)(b_in + l * 8 + 4);
        a[0] = fmaxf(fmaf(acc[0], di, bl0.x), 0.f);
        a[1] = fmaxf(fmaf(acc[1], di, bl0.y), 0.f);
        a[2] = fmaxf(fmaf(acc[2], di, bl0.z), 0.f);
        a[3] = fmaxf(fmaf(acc[3], di, bl0.w), 0.f);
        a[4] = fmaxf(fmaf(acc[4], di, bl1.x), 0.f);
        a[5] = fmaxf(fmaf(acc[5], di, bl1.y), 0.f);
        a[6] = fmaxf(fmaf(acc[6], di, bl1.z), 0.f);
        a[7] = fmaxf(fmaf(acc[7], di, bl1.w), 0.f);
    }

    // distributed 8x8 outer-product: lane (g,l): partials for out chunk g
    float part[8] = {0.f, 0.f, 0.f, 0.f, 0.f, 0.f, 0.f, 0.f};
#pragma unroll
    for (int q = 0; q < 8; ++q) {
        half8 wv = *(const half8*)&Wh[(l * 8 + q) * D + g * 8];
        float aq = a[q];
#pragma unroll
        for (int m = 0; m < 8; ++m)
            part[m] = fmaf(aq, (float)wv[m], part[m]);
    }
    // reduce across l (lane bits 0..2)
#pragma unroll
    for (int off = 1; off <= 4; off <<= 1) {
#pragma unroll
        for (int m = 0; m < 8; ++m)
            part[m] += __shfl_xor(part[m], off, 64);
    }
    if (l == 0) {
        half8 o;
#pragma unroll
        for (int m = 0; m < 8; ++m) o[m] = (_Float16)(part[m] * di);
        *(half8*)(Hout + (size_t)i * D + g * 8) = o;
    }
}

// ---------------- final pull (layer 3): AGG fp32 out for pooling ----------
__global__ void __launch_bounds__(256)
k_pull(const _Float16* __restrict__ H, const int* __restrict__ esrc,
       const int* __restrict__ base, const float* __restrict__ dinv,
       const float* __restrict__ b, float* __restrict__ AGG) {
    int i    = blockIdx.x * 4 + (threadIdx.x >> 6);
    int lane = threadIdx.x & 63;
    int g = lane >> 3, l = lane & 7;
    int s0 = base[i], s1 = base[i + 1];
    float acc[8] = {0.f, 0.f, 0.f, 0.f, 0.f, 0.f, 0.f, 0.f};
    if (g == 0) {
        half8 sv = *(const half8*)(H + (size_t)i * D + l * 8);
#pragma unroll
        for (int q = 0; q < 8; ++q) acc[q] = (float)sv[q];
    }

    int p = s0;
    while (p < s1) {
        int cnt = s1 - p;
        if (cnt > 64) cnt = 64;
        int ed = (lane < cnt) ? esrc[p + lane] : 0;
        int j = 0;
        for (; j + 32 <= cnt; j += 32) {
            int e0 = __shfl(ed, j + g, 64);
            int e1 = __shfl(ed, j + 8 + g, 64);
            int e2 = __shfl(ed, j + 16 + g, 64);
            int e3 = __shfl(ed, j + 24 + g, 64);
            half8 v0 = *(const half8*)(H + (size_t)e0 * D + l * 8);
            half8 v1 = *(const half8*)(H + (size_t)e1 * D + l * 8);
            half8 v2 = *(const half8*)(H + (size_t)e2 * D + l * 8);
            half8 v3 = *(const half8*)(H + (size_t)e3 * D + l * 8);
#pragma unroll
            for (int q = 0; q < 8; ++q)
                acc[q] += ((float)v0[q] + (float)v1[q]) + ((float)v2[q] + (float)v3[q]);
        }
        for (; j + 8 <= cnt; j += 8) {
            int e0 = __shfl(ed, j + g, 64);
            half8 v0 = *(const half8*)(H + (size_t)e0 * D + l * 8);
#pragma unroll
            for (int q = 0; q < 8; ++q) acc[q] += (float)v0[q];
        }
        if (j < cnt) {
            int idx = j + g;
            int e0 = __shfl(ed, idx & 63, 64);
            if (idx < cnt) {
                half8 v0 = *(const half8*)(H + (size_t)e0 * D + l * 8);
#pragma unroll
                for (int q = 0; q < 8; ++q) acc[q] += (float)v0[q];
            }
        }
        p += cnt;
    }
#pragma unroll
    for (int off = 8; off <= 32; off <<= 1) {
#pragma unroll
        for (int q = 0; q < 8; ++q)
            acc[q] += __shfl_xor(acc[q], off, 64);
    }

    if (g == 0) {
        float di = dinv[i];
        float4 bl0 = *(const float4*)(b + l * 8);
        float4 bl1 = *(const float4*)(b + l * 8 + 4);
        float4 o0 = { fmaf(acc[0], di, bl0.x), fmaf(acc[1], di, bl0.y),
                      fmaf(acc[2], di, bl0.z), fmaf(acc[3], di, bl0.w) };
        float4 o1 = { fmaf(acc[4], di, bl1.x), fmaf(acc[5], di, bl1.y),
                      fmaf(acc[6], di, bl1.z), fmaf(acc[7], di, bl1.w) };
        *(float4*)(AGG + (size_t)i * D + l * 8)     = o0;
        *(float4*)(AGG + (size_t)i * D + l * 8 + 4) = o1;
    }
}

// ---- segment-sorted pooling (+ fused counts via run lengths) ----
__global__ void __launch_bounds__(256)
k_pool_seg(const float* __restrict__ H, const int* __restrict__ seg,
           float* __restrict__ pooled, float* __restrict__ counts) {
    int wave = threadIdx.x >> 6;
    int lane = threadIdx.x & 63;
    int n0 = (blockIdx.x * 4 + wave) * 64;
    if (n0 >= N_NODES) return;
    int nEnd = n0 + 64;
    if (nEnd > N_NODES) nEnd = N_NODES;
    int cur = seg[n0];
    float acc = 0.0f;
    int run = 0;
    for (int n = n0; n < nEnd; ++n) {
        int gsg = seg[n];  // wave-uniform
        if (gsg != cur) {
            atomicAdd(&pooled[(size_t)cur * D + lane], acc);
            if (lane == 0) atomicAdd(&counts[cur], (float)run);
            acc = 0.0f; run = 0;
            cur = gsg;
        }
        acc += H[(size_t)n * D + lane];
        run += 1;
    }
    atomicAdd(&pooled[(size_t)cur * D + lane], acc);
    if (lane == 0) atomicAdd(&counts[cur], (float)run);
}

// ---------------- head ----------------
__global__ void k_out(const float* __restrict__ pooled, const float* __restrict__ counts,
                      const float* __restrict__ Wout, const float* __restrict__ bout,
                      float* __restrict__ out) {
    __shared__ float prow[D];
    int g = blockIdx.x;
    int t = threadIdx.x;
    if (t < D) prow[t] = pooled[(size_t)g * D + t] / fmaxf(counts[g], 1.0f);
    __syncthreads();
    if (t < N_TARGETS) {
        float acc = bout[t];
#pragma unroll
        for (int k = 0; k < D; ++k)
            acc = fmaf(prow[k], Wout[k * N_TARGETS + t], acc);
        out[g * N_TARGETS + t] = acc;
    }
}

// ---------------- driver ----------------

extern "C" void kernel_launch(void* const* d_in, const int* in_sizes, int n_in,
                              void* d_out, int out_size, void* d_ws, size_t ws_size,
                              hipStream_t stream) {
    const float* x    = (const float*)d_in[0];
    const float* W1   = (const float*)d_in[1];
    const float* b1   = (const float*)d_in[2];
    const float* W2   = (const float*)d_in[3];
    const float* b2   = (const float*)d_in[4];
    const float* W3   = (const float*)d_in[5];
    const float* b3   = (const float*)d_in[6];
    const float* Wout = (const float*)d_in[7];
    const float* bout = (const float*)d_in[8];
    const int*   eidx = (const int*)d_in[9];
    const int*   seg  = (const int*)d_in[10];
    const int* src = eidx;
    const int* dst = eidx + N_EDGES;
    float* out = (float*)d_out;

    // workspace layout (~47 MB)
    _Float16* H16A   = (_Float16*)d_ws;                       // 6.4M halfs
    _Float16* H16B   = H16A + (size_t)N_NODES * D;            // 6.4M halfs
    float*    AGG    = (float*)(H16B + (size_t)N_NODES * D);  // 6.4M floats
    int*      esrc   = (int*)(AGG + (size_t)N_NODES * D);     // 1.6M
    float*    dinv   = (float*)(esrc + N_EDGES);              // 100k
    int*      degc   = (int*)(dinv + N_NODES);                // 100k (deg, then cursor)
    int*      base   = degc + N_NODES;                        // 100k+1 (+pad)
    int*      bsum   = base + N_NODES + 4;                    // 512
    float*    pooled = (float*)(bsum + 512);                  // 32768
    float*    counts = pooled + N_GRAPHS * D;                 // 512

    const int NB = (N_NODES + 255) / 256;  // 391

    // ---- CSR build ----
    k_zero_i<<<NB, 256, 0, stream>>>(degc, N_NODES);
    k_deg<<<N_EDGES / 256, 256, 0, stream>>>(dst, degc);
    k_scan1<<<NB, 256, 0, stream>>>(degc, base, bsum, dinv);
    k_scan2<<<1, 512, 0, stream>>>(bsum, NB);
    k_scan3<<<NB, 256, 0, stream>>>(base, bsum, degc);
    k_fill<<<N_EDGES / 256, 256, 0, stream>>>(src, dst, base, degc, esrc);

    // ---- 3 GCN layers (mm1 separate; mm2/mm3 fused into pulls) ----
    const int MMB = (N_NODES + 63) / 64;  // 1563
    k_mm<<<MMB, 256, 0, stream>>>(x, W1, dinv, H16A);
    k_pullmm<<<N_NODES / 4, 256, 0, stream>>>(H16A, esrc, base, dinv, b1, W2, H16B);
    k_pullmm<<<N_NODES / 4, 256, 0, stream>>>(H16B, esrc, base, dinv, b2, W3, H16A);
    k_pull<<<N_NODES / 4, 256, 0, stream>>>(H16A, esrc, base, dinv, b3, AGG);

    // ---- mean pool (sorted-segment, fused counts) + head ----
    k_zero_f<<<(N_GRAPHS * D + N_GRAPHS + 255) / 256, 256, 0, stream>>>(pooled, N_GRAPHS * D + N_GRAPHS);
    k_pool_seg<<<NB, 256, 0, stream>>>(AGG, seg, pooled, counts);

    k_out<<<N_GRAPHS, 128, 0, stream>>>(pooled, counts, Wout, bout, out);
}

// Round 12
// 540.137 us; speedup vs baseline: 4.6677x; 1.0027x over previous
//
#include <hip/hip_runtime.h>

#define N_NODES   100000
#define N_EDGES   1600000
#define D         64
#define N_TARGETS 100
#define N_GRAPHS  512

typedef _Float16 half4 __attribute__((ext_vector_type(4)));
typedef _Float16 half8 __attribute__((ext_vector_type(8)));

// ---------------- utility ----------------

__global__ void k_zero_i(int* __restrict__ p, int n) {
    int i = blockIdx.x * blockDim.x + threadIdx.x;
    if (i < n) p[i] = 0;
}

// ---------------- CSR build (simple scatter fill — measured plateau) --------

__global__ void k_deg(const int* __restrict__ dst, int* __restrict__ deg) {
    int e = blockIdx.x * blockDim.x + threadIdx.x;
    if (e < N_EDGES) atomicAdd(&deg[dst[e]], 1);
}

// block-local exclusive scan of deg; also computes dinv (deg already loaded)
__global__ void k_scan1(const int* __restrict__ deg, int* __restrict__ base,
                        int* __restrict__ bsum, float* __restrict__ dinv) {
    __shared__ int s[256];
    int t = threadIdx.x, i = blockIdx.x * 256 + t;
    int v = (i < N_NODES) ? deg[i] : 0;
    if (i < N_NODES) dinv[i] = rsqrtf((float)v + 1.0f);  // +1 self-loop
    s[t] = v;
    __syncthreads();
    for (int off = 1; off < 256; off <<= 1) {
        int x = (t >= off) ? s[t - off] : 0;
        __syncthreads();
        s[t] += x;
        __syncthreads();
    }
    if (i < N_NODES) base[i] = s[t] - v;
    if (t == 255) bsum[blockIdx.x] = s[255];
}

__global__ void k_scan2(int* __restrict__ bsum, int nb) {
    __shared__ int s[512];
    int t = threadIdx.x;
    int v = (t < nb) ? bsum[t] : 0;
    s[t] = v;
    __syncthreads();
    for (int off = 1; off < 512; off <<= 1) {
        int x = (t >= off) ? s[t - off] : 0;
        __syncthreads();
        s[t] += x;
        __syncthreads();
    }
    if (t < nb) bsum[t] = s[t] - v;
}

// add block offsets; zero cursor; set base[N]=E; also zero pooled+counts
__global__ void k_scan3(int* __restrict__ base, const int* __restrict__ bsum,
                        int* __restrict__ cursor, float* __restrict__ poolz) {
    int i = blockIdx.x * blockDim.x + threadIdx.x;
    if (i < N_NODES) {
        base[i] += bsum[i >> 8];
        cursor[i] = 0;
    }
    if (i == 0) base[N_NODES] = N_EDGES;
    if (i < N_GRAPHS * D + N_GRAPHS) poolz[i] = 0.0f;
}

__global__ void k_fill(const int* __restrict__ src, const int* __restrict__ dst,
                       const int* __restrict__ base, int* __restrict__ cursor,
                       int* __restrict__ esrc) {
    int e = blockIdx.x * blockDim.x + threadIdx.x;
    if (e < N_EDGES) {
        int d = dst[e];
        int pos = base[d] + atomicAdd(&cursor[d], 1);
        esrc[pos] = src[e];
    }
}

// ------ matmul (layer 1 only): H16[row] = fp16( X[row] @ W * dinv[row] ) ----
__global__ void __launch_bounds__(256)
k_mm(const float* __restrict__ X, const float* __restrict__ W,
     const float* __restrict__ dinv, _Float16* __restrict__ Y16) {
    __shared__ float Xs[64][68];
    __shared__ float Ws[64][68];
    int tid = threadIdx.x;
    int r0  = blockIdx.x * 64;
    {
        int lr = tid >> 4;
        int lc = (tid & 15) * 4;
#pragma unroll
        for (int i = 0; i < 4; ++i) {
            int row = lr + 16 * i;
            *(float4*)&Ws[row][lc] = *(const float4*)(W + row * 64 + lc);
            int gr = r0 + row;
            if (gr < N_NODES)
                *(float4*)&Xs[row][lc] = *(const float4*)(X + (size_t)gr * 64 + lc);
        }
    }
    __syncthreads();

    int tx = (tid & 15) * 4;
    int ty = (tid >> 4) * 4;
    float acc[4][4] = {{0.f}};

#pragma unroll
    for (int kk = 0; kk < 16; ++kk) {
        float4 a[4], w[4];
#pragma unroll
        for (int r = 0; r < 4; ++r) a[r] = *(float4*)&Xs[ty + r][kk * 4];
#pragma unroll
        for (int k = 0; k < 4; ++k) w[k] = *(float4*)&Ws[kk * 4 + k][tx];
#pragma unroll
        for (int r = 0; r < 4; ++r) {
#pragma unroll
            for (int k = 0; k < 4; ++k) {
                float av = ((const float*)&a[r])[k];
                acc[r][0] = fmaf(av, w[k].x, acc[r][0]);
                acc[r][1] = fmaf(av, w[k].y, acc[r][1]);
                acc[r][2] = fmaf(av, w[k].z, acc[r][2]);
                acc[r][3] = fmaf(av, w[k].w, acc[r][3]);
            }
        }
    }

#pragma unroll
    for (int r = 0; r < 4; ++r) {
        int gr = r0 + ty + r;
        if (gr < N_NODES) {
            float di = dinv[gr];
            half4 o;
            o.x = (_Float16)(acc[r][0] * di);
            o.y = (_Float16)(acc[r][1] * di);
            o.z = (_Float16)(acc[r][2] * di);
            o.w = (_Float16)(acc[r][3] * di);
            *(half4*)(Y16 + (size_t)gr * 64 + tx) = o;
        }
    }
}

// ---- fused pull + next-layer matmul (low-DS epilogue, R11 structure) ----
__global__ void __launch_bounds__(256)
k_pullmm(const _Float16* __restrict__ H, const int* __restrict__ esrc,
         const int* __restrict__ base, const float* __restrict__ dinv,
         const float* __restrict__ b_in, const float* __restrict__ W,
         _Float16* __restrict__ Hout) {
    __shared__ _Float16 Wh[D * D];   // [k][f] fp16, 8KB
    {
        for (int idx = threadIdx.x; idx < (D * D) / 8; idx += 256) {
            float4 w0 = *(const float4*)(W + idx * 8);
            float4 w1 = *(const float4*)(W + idx * 8 + 4);
            half8 h;
            h[0] = (_Float16)w0.x; h[1] = (_Float16)w0.y;
            h[2] = (_Float16)w0.z; h[3] = (_Float16)w0.w;
            h[4] = (_Float16)w1.x; h[5] = (_Float16)w1.y;
            h[6] = (_Float16)w1.z; h[7] = (_Float16)w1.w;
            *(half8*)&Wh[idx * 8] = h;
        }
    }
    __syncthreads();

    int i    = blockIdx.x * 4 + (threadIdx.x >> 6);
    int lane = threadIdx.x & 63;
    int g = lane >> 3, l = lane & 7;
    int s0 = base[i], s1 = base[i + 1];
    float acc[8] = {0.f, 0.f, 0.f, 0.f, 0.f, 0.f, 0.f, 0.f};
    if (g == 0) {
        half8 sv = *(const half8*)(H + (size_t)i * D + l * 8);
#pragma unroll
        for (int q = 0; q < 8; ++q) acc[q] = (float)sv[q];
    }

    int p = s0;
    while (p < s1) {
        int cnt = s1 - p;
        if (cnt > 64) cnt = 64;
        int ed = (lane < cnt) ? esrc[p + lane] : 0;
        int j = 0;
        for (; j + 32 <= cnt; j += 32) {
            int e0 = __shfl(ed, j + g, 64);
            int e1 = __shfl(ed, j + 8 + g, 64);
            int e2 = __shfl(ed, j + 16 + g, 64);
            int e3 = __shfl(ed, j + 24 + g, 64);
            half8 v0 = *(const half8*)(H + (size_t)e0 * D + l * 8);
            half8 v1 = *(const half8*)(H + (size_t)e1 * D + l * 8);
            half8 v2 = *(const half8*)(H + (size_t)e2 * D + l * 8);
            half8 v3 = *(const half8*)(H + (size_t)e3 * D + l * 8);
#pragma unroll
            for (int q = 0; q < 8; ++q)
                acc[q] += ((float)v0[q] + (float)v1[q]) + ((float)v2[q] + (float)v3[q]);
        }
        for (; j + 8 <= cnt; j += 8) {
            int e0 = __shfl(ed, j + g, 64);
            half8 v0 = *(const half8*)(H + (size_t)e0 * D + l * 8);
#pragma unroll
            for (int q = 0; q < 8; ++q) acc[q] += (float)v0[q];
        }
        if (j < cnt) {
            int idx = j + g;
            int e0 = __shfl(ed, idx & 63, 64);
            if (idx < cnt) {
                half8 v0 = *(const half8*)(H + (size_t)e0 * D + l * 8);
#pragma unroll
                for (int q = 0; q < 8; ++q) acc[q] += (float)v0[q];
            }
        }
        p += cnt;
    }
#pragma unroll
    for (int off = 8; off <= 32; off <<= 1) {
#pragma unroll
        for (int q = 0; q < 8; ++q)
            acc[q] += __shfl_xor(acc[q], off, 64);
    }

    float di = dinv[i];
    float a[8];
    {
        float4 bl0 = *(const float4*)(b_in + l * 8);
        float4 bl1 = *(const float4*)(b_in + l * 8 + 4);
        a[0] = fmaxf(fmaf(acc[0], di, bl0.x), 0.f);
        a[1] = fmaxf(fmaf(acc[1], di, bl0.y), 0.f);
        a[2] = fmaxf(fmaf(acc[2], di, bl0.z), 0.f);
        a[3] = fmaxf(fmaf(acc[3], di, bl0.w), 0.f);
        a[4] = fmaxf(fmaf(acc[4], di, bl1.x), 0.f);
        a[5] = fmaxf(fmaf(acc[5], di, bl1.y), 0.f);
        a[6] = fmaxf(fmaf(acc[6], di, bl1.z), 0.f);
        a[7] = fmaxf(fmaf(acc[7], di, bl1.w), 0.f);
    }

    float part[8] = {0.f, 0.f, 0.f, 0.f, 0.f, 0.f, 0.f, 0.f};
#pragma unroll
    for (int q = 0; q < 8; ++q) {
        half8 wv = *(const half8*)&Wh[(l * 8 + q) * D + g * 8];
        float aq = a[q];
#pragma unroll
        for (int m = 0; m < 8; ++m)
            part[m] = fmaf(aq, (float)wv[m], part[m]);
    }
#pragma unroll
    for (int off = 1; off <= 4; off <<= 1) {
#pragma unroll
        for (int m = 0; m < 8; ++m)
            part[m] += __shfl_xor(part[m], off, 64);
    }
    if (l == 0) {
        half8 o;
#pragma unroll
        for (int m = 0; m < 8; ++m) o[m] = (_Float16)(part[m] * di);
        *(half8*)(Hout + (size_t)i * D + g * 8) = o;
    }
}

// ---------------- final pull (layer 3): fp16 AGG out for pooling ----------
__global__ void __launch_bounds__(256)
k_pull(const _Float16* __restrict__ H, const int* __restrict__ esrc,
       const int* __restrict__ base, const float* __restrict__ dinv,
       const float* __restrict__ b, _Float16* __restrict__ AGG16) {
    int i    = blockIdx.x * 4 + (threadIdx.x >> 6);
    int lane = threadIdx.x & 63;
    int g = lane >> 3, l = lane & 7;
    int s0 = base[i], s1 = base[i + 1];
    float acc[8] = {0.f, 0.f, 0.f, 0.f, 0.f, 0.f, 0.f, 0.f};
    if (g == 0) {
        half8 sv = *(const half8*)(H + (size_t)i * D + l * 8);
#pragma unroll
        for (int q = 0; q < 8; ++q) acc[q] = (float)sv[q];
    }

    int p = s0;
    while (p < s1) {
        int cnt = s1 - p;
        if (cnt > 64) cnt = 64;
        int ed = (lane < cnt) ? esrc[p + lane] : 0;
        int j = 0;
        for (; j + 32 <= cnt; j += 32) {
            int e0 = __shfl(ed, j + g, 64);
            int e1 = __shfl(ed, j + 8 + g, 64);
            int e2 = __shfl(ed, j + 16 + g, 64);
            int e3 = __shfl(ed, j + 24 + g, 64);
            half8 v0 = *(const half8*)(H + (size_t)e0 * D + l * 8);
            half8 v1 = *(const half8*)(H + (size_t)e1 * D + l * 8);
            half8 v2 = *(const half8*)(H + (size_t)e2 * D + l * 8);
            half8 v3 = *(const half8*)(H + (size_t)e3 * D + l * 8);
#pragma unroll
            for (int q = 0; q < 8; ++q)
                acc[q] += ((float)v0[q] + (float)v1[q]) + ((float)v2[q] + (float)v3[q]);
        }
        for (; j + 8 <= cnt; j += 8) {
            int e0 = __shfl(ed, j + g, 64);
            half8 v0 = *(const half8*)(H + (size_t)e0 * D + l * 8);
#pragma unroll
            for (int q = 0; q < 8; ++q) acc[q] += (float)v0[q];
        }
        if (j < cnt) {
            int idx = j + g;
            int e0 = __shfl(ed, idx & 63, 64);
            if (idx < cnt) {
                half8 v0 = *(const half8*)(H + (size_t)e0 * D + l * 8);
#pragma unroll
                for (int q = 0; q < 8; ++q) acc[q] += (float)v0[q];
            }
        }
        p += cnt;
    }
#pragma unroll
    for (int off = 8; off <= 32; off <<= 1) {
#pragma unroll
        for (int q = 0; q < 8; ++q)
            acc[q] += __shfl_xor(acc[q], off, 64);
    }

    if (g == 0) {
        float di = dinv[i];
        float4 bl0 = *(const float4*)(b + l * 8);
        float4 bl1 = *(const float4*)(b + l * 8 + 4);
        half8 o;
        o[0] = (_Float16)fmaf(acc[0], di, bl0.x);
        o[1] = (_Float16)fmaf(acc[1], di, bl0.y);
        o[2] = (_Float16)fmaf(acc[2], di, bl0.z);
        o[3] = (_Float16)fmaf(acc[3], di, bl0.w);
        o[4] = (_Float16)fmaf(acc[4], di, bl1.x);
        o[5] = (_Float16)fmaf(acc[5], di, bl1.y);
        o[6] = (_Float16)fmaf(acc[6], di, bl1.z);
        o[7] = (_Float16)fmaf(acc[7], di, bl1.w);
        *(half8*)(AGG16 + (size_t)i * D + l * 8) = o;
    }
}

// ---- segment-sorted pooling (fp16 in, fp32 accumulate, fused counts) ----
__global__ void __launch_bounds__(256)
k_pool_seg(const _Float16* __restrict__ H16, const int* __restrict__ seg,
           float* __restrict__ pooled, float* __restrict__ counts) {
    int wave = threadIdx.x >> 6;
    int lane = threadIdx.x & 63;
    int n0 = (blockIdx.x * 4 + wave) * 64;
    if (n0 >= N_NODES) return;
    int nEnd = n0 + 64;
    if (nEnd > N_NODES) nEnd = N_NODES;
    int cur = seg[n0];
    float acc = 0.0f;
    int run = 0;
    for (int n = n0; n < nEnd; ++n) {
        int gsg = seg[n];  // wave-uniform
        if (gsg != cur) {
            atomicAdd(&pooled[(size_t)cur * D + lane], acc);
            if (lane == 0) atomicAdd(&counts[cur], (float)run);
            acc = 0.0f; run = 0;
            cur = gsg;
        }
        acc += (float)H16[(size_t)n * D + lane];
        run += 1;
    }
    atomicAdd(&pooled[(size_t)cur * D + lane], acc);
    if (lane == 0) atomicAdd(&counts[cur], (float)run);
}

// ---------------- head ----------------
__global__ void k_out(const float* __restrict__ pooled, const float* __restrict__ counts,
                      const float* __restrict__ Wout, const float* __restrict__ bout,
                      float* __restrict__ out) {
    __shared__ float prow[D];
    int g = blockIdx.x;
    int t = threadIdx.x;
    if (t < D) prow[t] = pooled[(size_t)g * D + t] / fmaxf(counts[g], 1.0f);
    __syncthreads();
    if (t < N_TARGETS) {
        float acc = bout[t];
#pragma unroll
        for (int k = 0; k < D; ++k)
            acc = fmaf(prow[k], Wout[k * N_TARGETS + t], acc);
        out[g * N_TARGETS + t] = acc;
    }
}

// ---------------- driver ----------------

extern "C" void kernel_launch(void* const* d_in, const int* in_sizes, int n_in,
                              void* d_out, int out_size, void* d_ws, size_t ws_size,
                              hipStream_t stream) {
    const float* x    = (const float*)d_in[0];
    const float* W1   = (const float*)d_in[1];
    const float* b1   = (const float*)d_in[2];
    const float* W2   = (const float*)d_in[3];
    const float* b2   = (const float*)d_in[4];
    const float* W3   = (const float*)d_in[5];
    const float* b3   = (const float*)d_in[6];
    const float* Wout = (const float*)d_in[7];
    const float* bout = (const float*)d_in[8];
    const int*   eidx = (const int*)d_in[9];
    const int*   seg  = (const int*)d_in[10];
    const int* src = eidx;
    const int* dst = eidx + N_EDGES;
    float* out = (float*)d_out;

    // workspace layout (~34 MB). AGG16 aliases H16B (dead after pullmm#2).
    _Float16* H16A   = (_Float16*)d_ws;                       // 6.4M halfs
    _Float16* H16B   = H16A + (size_t)N_NODES * D;            // 6.4M halfs
    _Float16* AGG16  = H16B;                                  // alias
    int*      esrc   = (int*)(H16B + (size_t)N_NODES * D);    // 1.6M
    float*    dinv   = (float*)(esrc + N_EDGES);              // 100k
    int*      degc   = (int*)(dinv + N_NODES);                // 100k (deg, then cursor)
    int*      base   = degc + N_NODES;                        // 100k+1 (+pad)
    int*      bsum   = base + N_NODES + 4;                    // 512
    float*    pooled = (float*)(bsum + 512);                  // 32768
    float*    counts = pooled + N_GRAPHS * D;                 // 512 (contiguous)

    const int NB = (N_NODES + 255) / 256;  // 391

    // ---- CSR build ----
    k_zero_i<<<NB, 256, 0, stream>>>(degc, N_NODES);
    k_deg<<<N_EDGES / 256, 256, 0, stream>>>(dst, degc);
    k_scan1<<<NB, 256, 0, stream>>>(degc, base, bsum, dinv);
    k_scan2<<<1, 512, 0, stream>>>(bsum, NB);
    k_scan3<<<NB, 256, 0, stream>>>(base, bsum, degc, pooled);  // zeroes pooled+counts too
    k_fill<<<N_EDGES / 256, 256, 0, stream>>>(src, dst, base, degc, esrc);

    // ---- 3 GCN layers (mm1 separate; mm2/mm3 fused into pulls) ----
    const int MMB = (N_NODES + 63) / 64;  // 1563
    k_mm<<<MMB, 256, 0, stream>>>(x, W1, dinv, H16A);
    k_pullmm<<<N_NODES / 4, 256, 0, stream>>>(H16A, esrc, base, dinv, b1, W2, H16B);
    k_pullmm<<<N_NODES / 4, 256, 0, stream>>>(H16B, esrc, base, dinv, b2, W3, H16A);
    k_pull<<<N_NODES / 4, 256, 0, stream>>>(H16A, esrc, base, dinv, b3, AGG16);

    // ---- mean pool (sorted-segment, fused counts) + head ----
    k_pool_seg<<<NB, 256, 0, stream>>>(AGG16, seg, pooled, counts);
    k_out<<<N_GRAPHS, 128, 0, stream>>>(pooled, counts, Wout, bout, out);
}